// Round 1
// baseline (8080.827 us; speedup 1.0000x reference)
//
#include <hip/hip_runtime.h>
#include <hip/hip_bf16.h>

#define V 196608
#define NNZ (9 * V)
#define B 4
#define FIN 32
#define FOUT 64
#define K 5
#define C 128           // FIN*B feature columns per vertex
#define XELEMS (V * C)  // 25,165,824 floats per cheb buffer

// ---------------------------------------------------------------------------
// x0[v*128 + fin*4 + b] = inputs[(b*V + v)*32 + fin]
__global__ void build_x0(const float* __restrict__ inp, float* __restrict__ x0) {
    int idx = blockIdx.x * 256 + threadIdx.x;
    if (idx >= XELEMS) return;
    int c = idx & (C - 1);
    int v = idx >> 7;
    int fin = c >> 2;
    int b = c & 3;
    x0[idx] = inp[((b * V + v) << 5) + fin];
}

// ---------------------------------------------------------------------------
// scatter-add SpMM: one wave (64 lanes) per edge, float2 per lane
__global__ void spmm_scatter(const int* __restrict__ rows, const int* __restrict__ cols,
                             const float* __restrict__ vals, const float* __restrict__ x,
                             float* __restrict__ y) {
    int wave = (blockIdx.x * 256 + threadIdx.x) >> 6;
    int lane = threadIdx.x & 63;
    if (wave >= NNZ) return;
    int r = rows[wave];
    int c = cols[wave];
    float val = vals[wave];
    const float2 xv = *reinterpret_cast<const float2*>(x + c * C + lane * 2);
    float* yp = y + r * C + lane * 2;
    unsafeAtomicAdd(yp, val * xv.x);
    unsafeAtomicAdd(yp + 1, val * xv.y);
}

// ---------------------------------------------------------------------------
// in-place Chebyshev combine: t = 2*t - x_{k-2}
__global__ void cheb_combine(float* __restrict__ t, const float* __restrict__ xm2) {
    int idx = blockIdx.x * 256 + threadIdx.x;
    if (idx >= XELEMS) return;
    t[idx] = 2.0f * t[idx] - xm2[idx];
}

// ---------------------------------------------------------------------------
// accumulate term k into out.
// out[(b*V+v)*64 + o] (+)= sum_fin xk[v*128 + fin*4 + b] * w[(fin*5+k)*64 + o]
// first=1: out = bias[o] + sum   (initializes poisoned buffer)
template <int FIRST>
__global__ void accum_term(const float* __restrict__ xk, const float* __restrict__ w,
                           const float* __restrict__ bias, float* __restrict__ out, int k) {
    int idx = blockIdx.x * 256 + threadIdx.x;  // < B*V*FOUT = 50,331,648
    int o = idx & 63;
    int bv = idx >> 6;
    int v = bv % V;
    int b = bv / V;
    const float* xr = xk + v * C + b;
    float acc = FIRST ? bias[o] : out[idx];
    const float* wr = w + k * 64 + o;
#pragma unroll
    for (int fin = 0; fin < FIN; ++fin) {
        acc += xr[fin * 4] * wr[fin * 5 * 64];
    }
    out[idx] = acc;
}

// ---------------------------------------------------------------------------
extern "C" void kernel_launch(void* const* d_in, const int* in_sizes, int n_in,
                              void* d_out, int out_size, void* d_ws, size_t ws_size,
                              hipStream_t stream) {
    const int* lap_rows = (const int*)d_in[0];
    const int* lap_cols = (const int*)d_in[1];
    const float* lap_vals = (const float*)d_in[2];
    const float* inputs = (const float*)d_in[3];
    const float* weight = (const float*)d_in[4];  // flat [160][64] == Weff
    const float* bias = (const float*)d_in[5];
    float* out = (float*)d_out;

    float* buf0 = (float*)d_ws;
    float* buf1 = buf0 + XELEMS;
    float* buf2 = buf1 + XELEMS;

    const int elem_blocks = (XELEMS + 255) / 256;       // 98304
    const int spmm_blocks = (NNZ * 64 + 255) / 256;     // 442368
    const int out_blocks = (B * V * FOUT + 255) / 256;  // 196608
    const size_t xbytes = (size_t)XELEMS * sizeof(float);

    // k = 0
    build_x0<<<elem_blocks, 256, 0, stream>>>(inputs, buf0);
    accum_term<1><<<out_blocks, 256, 0, stream>>>(buf0, weight, bias, out, 0);

    // k = 1 : x1 = L x0
    hipMemsetAsync(buf1, 0, xbytes, stream);
    spmm_scatter<<<spmm_blocks, 256, 0, stream>>>(lap_rows, lap_cols, lap_vals, buf0, buf1);
    accum_term<0><<<out_blocks, 256, 0, stream>>>(buf1, weight, bias, out, 1);

    // k = 2 : x2 = 2 L x1 - x0
    hipMemsetAsync(buf2, 0, xbytes, stream);
    spmm_scatter<<<spmm_blocks, 256, 0, stream>>>(lap_rows, lap_cols, lap_vals, buf1, buf2);
    cheb_combine<<<elem_blocks, 256, 0, stream>>>(buf2, buf0);
    accum_term<0><<<out_blocks, 256, 0, stream>>>(buf2, weight, bias, out, 2);

    // k = 3 : x3 = 2 L x2 - x1
    hipMemsetAsync(buf0, 0, xbytes, stream);
    spmm_scatter<<<spmm_blocks, 256, 0, stream>>>(lap_rows, lap_cols, lap_vals, buf2, buf0);
    cheb_combine<<<elem_blocks, 256, 0, stream>>>(buf0, buf1);
    accum_term<0><<<out_blocks, 256, 0, stream>>>(buf0, weight, bias, out, 3);

    // k = 4 : x4 = 2 L x3 - x2
    hipMemsetAsync(buf1, 0, xbytes, stream);
    spmm_scatter<<<spmm_blocks, 256, 0, stream>>>(lap_rows, lap_cols, lap_vals, buf0, buf1);
    cheb_combine<<<elem_blocks, 256, 0, stream>>>(buf1, buf2);
    accum_term<0><<<out_blocks, 256, 0, stream>>>(buf1, weight, bias, out, 4);
}

// Round 2
// 2700.729 us; speedup vs baseline: 2.9921x; 2.9921x over previous
//
#include <hip/hip_runtime.h>
#include <hip/hip_bf16.h>

#define V 196608
#define NNZ (9 * V)
#define B 4
#define FIN 32
#define FOUT 64
#define K 5
#define C 128           // FIN*B feature columns per vertex
#define XELEMS (V * C)  // 25,165,824 floats per cheb buffer

// ---------------------------------------------------------------------------
// x0[v*128 + fin*4 + b] = inputs[(b*V + v)*32 + fin]
__global__ void build_x0(const float* __restrict__ inp, float* __restrict__ x0) {
    int idx = blockIdx.x * 256 + threadIdx.x;
    if (idx >= XELEMS) return;
    int c = idx & (C - 1);
    int v = idx >> 7;
    int fin = c >> 2;
    int b = c & 3;
    x0[idx] = inp[((b * V + v) << 5) + fin];
}

// ---------------------------------------------------------------------------
// CSR build step 1: histogram row counts into cnt[] (pre-zeroed)
__global__ void hist_rows(const int* __restrict__ rows, int* __restrict__ cnt) {
    int e = blockIdx.x * 256 + threadIdx.x;
    if (e < NNZ) atomicAdd(&cnt[rows[e]], 1);
}

// ---------------------------------------------------------------------------
// CSR build step 2: single-block exclusive scan of cnt[V] -> rowptr[V+1],
// also writes the row cursors (= start offsets) for the scatter step.
// V = 196608 = 192 chunks of 1024.
__global__ void scan_counts(const int* __restrict__ cnt, int* __restrict__ rowptr,
                            int* __restrict__ cursor) {
    __shared__ int wsum[16];
    __shared__ int carry_s;
    const int tid = threadIdx.x;
    const int lane = tid & 63;
    const int wid = tid >> 6;
    if (tid == 0) carry_s = 0;
    __syncthreads();
    for (int base = 0; base < V; base += 1024) {
        int v = cnt[base + tid];
        // inclusive scan within wave
        int x = v;
#pragma unroll
        for (int off = 1; off < 64; off <<= 1) {
            int t = __shfl_up(x, off, 64);
            if (lane >= off) x += t;
        }
        if (lane == 63) wsum[wid] = x;
        __syncthreads();
        if (wid == 0 && lane < 16) {
            int s = wsum[lane];
            int y = s;
#pragma unroll
            for (int off = 1; off < 16; off <<= 1) {
                int t = __shfl_up(y, off, 16);
                if (lane >= off) y += t;
            }
            wsum[lane] = y - s;  // exclusive wave offset
        }
        __syncthreads();
        int incl = x + wsum[wid];
        int carry = carry_s;
        int excl = carry + incl - v;
        rowptr[base + tid] = excl;
        cursor[base + tid] = excl;
        __syncthreads();
        if (tid == 1023) carry_s = excl + v;
        __syncthreads();
    }
    if (tid == 0) rowptr[V] = carry_s;
}

// ---------------------------------------------------------------------------
// CSR build step 3: scatter edges into row-grouped order
__global__ void scatter_edges(const int* __restrict__ rows, const int* __restrict__ cols,
                              const float* __restrict__ vals, int* __restrict__ cursor,
                              int* __restrict__ ccol, float* __restrict__ cval) {
    int e = blockIdx.x * 256 + threadIdx.x;
    if (e >= NNZ) return;
    int r = rows[e];
    int p = atomicAdd(&cursor[r], 1);
    ccol[p] = cols[e];
    cval[p] = vals[e];
}

// ---------------------------------------------------------------------------
// gather SpMM: one wave per row. y[r] = sum_e val_e * x[col_e]  (COMBINE=0)
//              y[r] = 2*sum - xm2[r]                            (COMBINE=1)
template <int COMBINE>
__global__ void spmm_gather(const int* __restrict__ rowptr, const int* __restrict__ ccol,
                            const float* __restrict__ cval, const float* __restrict__ x,
                            const float* __restrict__ xm2, float* __restrict__ y) {
    int row = (blockIdx.x * 256 + threadIdx.x) >> 6;
    int lane = threadIdx.x & 63;
    if (row >= V) return;
    int s = rowptr[row];
    int e = rowptr[row + 1];
    float2 acc = {0.0f, 0.0f};
    for (int i = s; i < e; ++i) {
        int c = ccol[i];
        float v = cval[i];
        float2 xv = *reinterpret_cast<const float2*>(x + c * C + lane * 2);
        acc.x += v * xv.x;
        acc.y += v * xv.y;
    }
    float* yp = y + row * C + lane * 2;
    if (COMBINE) {
        float2 p = *reinterpret_cast<const float2*>(xm2 + row * C + lane * 2);
        acc.x = 2.0f * acc.x - p.x;
        acc.y = 2.0f * acc.y - p.y;
    }
    *reinterpret_cast<float2*>(yp) = acc;
}

// ---------------------------------------------------------------------------
// accumulate term k into out, 4 vertices per thread (amortize w loads).
// out[(b*V+v)*64 + o] (+)= sum_fin xk[v*128 + fin*4 + b] * w[(fin*5+k)*64 + o]
template <int FIRST>
__global__ void accum_term4(const float* __restrict__ xk, const float* __restrict__ w,
                            const float* __restrict__ bias, float* __restrict__ out, int k) {
    int idx = blockIdx.x * 256 + threadIdx.x;  // (b, v/4, o) : B*(V/4)*64 threads
    int o = idx & 63;
    int g = idx >> 6;
    int v = (g % (V / 4)) * 4;
    int b = g / (V / 4);
    const float* xr = xk + v * C + b;  // wave-uniform -> scalar loads
    size_t obase = ((size_t)(b * V + v)) * 64 + o;
    float a0, a1, a2, a3;
    if (FIRST) {
        float bs = bias[o];
        a0 = a1 = a2 = a3 = bs;
    } else {
        a0 = out[obase];
        a1 = out[obase + 64];
        a2 = out[obase + 128];
        a3 = out[obase + 192];
    }
    const float* wr = w + k * 64 + o;
#pragma unroll
    for (int fin = 0; fin < FIN; ++fin) {
        float wv = wr[fin * 5 * 64];
        a0 += xr[fin * 4] * wv;
        a1 += xr[fin * 4 + 128] * wv;
        a2 += xr[fin * 4 + 256] * wv;
        a3 += xr[fin * 4 + 384] * wv;
    }
    out[obase] = a0;
    out[obase + 64] = a1;
    out[obase + 128] = a2;
    out[obase + 192] = a3;
}

// ---------------------------------------------------------------------------
extern "C" void kernel_launch(void* const* d_in, const int* in_sizes, int n_in,
                              void* d_out, int out_size, void* d_ws, size_t ws_size,
                              hipStream_t stream) {
    const int* lap_rows = (const int*)d_in[0];
    const int* lap_cols = (const int*)d_in[1];
    const float* lap_vals = (const float*)d_in[2];
    const float* inputs = (const float*)d_in[3];
    const float* weight = (const float*)d_in[4];  // flat [160][64] == effective W
    const float* bias = (const float*)d_in[5];
    float* out = (float*)d_out;

    char* p = (char*)d_ws;
    auto alloc = [&](size_t bytes) {
        char* r = p;
        p += (bytes + 511) & ~(size_t)511;
        return r;
    };
    int* rowptr = (int*)alloc((size_t)(V + 1) * 4);
    int* cursor = (int*)alloc((size_t)V * 4);
    int* ccol = (int*)alloc((size_t)NNZ * 4);
    float* cval = (float*)alloc((size_t)NNZ * 4);
    float* cb0 = (float*)alloc((size_t)XELEMS * 4);
    float* cb1 = (float*)alloc((size_t)XELEMS * 4);
    float* cb2 = (float*)alloc((size_t)XELEMS * 4);

    const int edge_blocks = (NNZ + 255) / 256;          // 6912
    const int elem_blocks = (XELEMS + 255) / 256;       // 98304
    const int spmm_blocks = (V * 64 + 255) / 256;       // 49152 (wave per row)
    const int acc_blocks = (B * (V / 4) * 64) / 256;    // 49152

    // ---- CSR build ----
    hipMemsetAsync(cursor, 0, (size_t)V * 4, stream);
    hist_rows<<<edge_blocks, 256, 0, stream>>>(lap_rows, cursor);
    scan_counts<<<1, 1024, 0, stream>>>(cursor, rowptr, cursor);
    scatter_edges<<<edge_blocks, 256, 0, stream>>>(lap_rows, lap_cols, lap_vals, cursor, ccol, cval);

    // ---- k = 0 ----
    build_x0<<<elem_blocks, 256, 0, stream>>>(inputs, cb0);
    accum_term4<1><<<acc_blocks, 256, 0, stream>>>(cb0, weight, bias, out, 0);

    // ---- k = 1 : x1 = L x0 ----
    spmm_gather<0><<<spmm_blocks, 256, 0, stream>>>(rowptr, ccol, cval, cb0, nullptr, cb1);
    accum_term4<0><<<acc_blocks, 256, 0, stream>>>(cb1, weight, bias, out, 1);

    // ---- k = 2 : x2 = 2 L x1 - x0 ----
    spmm_gather<1><<<spmm_blocks, 256, 0, stream>>>(rowptr, ccol, cval, cb1, cb0, cb2);
    accum_term4<0><<<acc_blocks, 256, 0, stream>>>(cb2, weight, bias, out, 2);

    // ---- k = 3 : x3 = 2 L x2 - x1 ----
    spmm_gather<1><<<spmm_blocks, 256, 0, stream>>>(rowptr, ccol, cval, cb2, cb1, cb0);
    accum_term4<0><<<acc_blocks, 256, 0, stream>>>(cb0, weight, bias, out, 3);

    // ---- k = 4 : x4 = 2 L x3 - x2 ----
    spmm_gather<1><<<spmm_blocks, 256, 0, stream>>>(rowptr, ccol, cval, cb0, cb2, cb1);
    accum_term4<0><<<acc_blocks, 256, 0, stream>>>(cb1, weight, bias, out, 4);
}

// Round 3
// 1991.772 us; speedup vs baseline: 4.0571x; 1.3559x over previous
//
#include <hip/hip_runtime.h>
#include <hip/hip_bf16.h>

#define V 196608
#define NNZ (9 * V)
#define B 4
#define FIN 32
#define FOUT 64
#define K 5
#define C 128           // FIN*B feature columns per vertex
#define XELEMS (V * C)  // 25,165,824 floats per cheb buffer
#define WPB 4           // waves per block
#define VPW 4           // vertices per wave inner group

// ---------------------------------------------------------------------------
// x0[v*128 + fin*4 + b] = inputs[(b*V + v)*32 + fin]
__global__ void build_x0(const float* __restrict__ inp, float* __restrict__ x0) {
    int idx = blockIdx.x * 256 + threadIdx.x;
    if (idx >= XELEMS) return;
    int c = idx & (C - 1);
    int v = idx >> 7;
    int fin = c >> 2;
    int b = c & 3;
    x0[idx] = inp[((b * V + v) << 5) + fin];
}

// ---------------------------------------------------------------------------
// CSR build step 1: histogram row counts into cnt[] (pre-zeroed)
__global__ void hist_rows(const int* __restrict__ rows, int* __restrict__ cnt) {
    int e = blockIdx.x * 256 + threadIdx.x;
    if (e < NNZ) atomicAdd(&cnt[rows[e]], 1);
}

// ---------------------------------------------------------------------------
// CSR build step 2: single-block exclusive scan of cnt[V] -> rowptr[V+1] + cursors
__global__ void scan_counts(const int* __restrict__ cnt, int* __restrict__ rowptr,
                            int* __restrict__ cursor) {
    __shared__ int wsum[16];
    __shared__ int carry_s;
    const int tid = threadIdx.x;
    const int lane = tid & 63;
    const int wid = tid >> 6;
    if (tid == 0) carry_s = 0;
    __syncthreads();
    for (int base = 0; base < V; base += 1024) {
        int v = cnt[base + tid];
        int x = v;
#pragma unroll
        for (int off = 1; off < 64; off <<= 1) {
            int t = __shfl_up(x, off, 64);
            if (lane >= off) x += t;
        }
        if (lane == 63) wsum[wid] = x;
        __syncthreads();
        if (wid == 0 && lane < 16) {
            int s = wsum[lane];
            int y = s;
#pragma unroll
            for (int off = 1; off < 16; off <<= 1) {
                int t = __shfl_up(y, off, 16);
                if (lane >= off) y += t;
            }
            wsum[lane] = y - s;
        }
        __syncthreads();
        int incl = x + wsum[wid];
        int carry = carry_s;
        int excl = carry + incl - v;
        rowptr[base + tid] = excl;
        cursor[base + tid] = excl;
        __syncthreads();
        if (tid == 1023) carry_s = excl + v;
        __syncthreads();
    }
    if (tid == 0) rowptr[V] = carry_s;
}

// ---------------------------------------------------------------------------
// CSR build step 3: scatter edges into row-grouped order
__global__ void scatter_edges(const int* __restrict__ rows, const int* __restrict__ cols,
                              const float* __restrict__ vals, int* __restrict__ cursor,
                              int* __restrict__ ccol, float* __restrict__ cval) {
    int e = blockIdx.x * 256 + threadIdx.x;
    if (e >= NNZ) return;
    int r = rows[e];
    int p = atomicAdd(&cursor[r], 1);
    ccol[p] = cols[e];
    cval[p] = vals[e];
}

// ---------------------------------------------------------------------------
// gather SpMM: one wave per row. y[r] = sum_e val_e * x[col_e]  (COMBINE=0)
//              y[r] = 2*sum - xm2[r]                            (COMBINE=1)
template <int COMBINE>
__global__ void spmm_gather(const int* __restrict__ rowptr, const int* __restrict__ ccol,
                            const float* __restrict__ cval, const float* __restrict__ x,
                            const float* __restrict__ xm2, float* __restrict__ y) {
    int row = (blockIdx.x * 256 + threadIdx.x) >> 6;
    int lane = threadIdx.x & 63;
    if (row >= V) return;
    int s = rowptr[row];
    int e = rowptr[row + 1];
    float2 acc = {0.0f, 0.0f};
    for (int i = s; i < e; ++i) {
        int c = ccol[i];
        float v = cval[i];
        float2 xv = *reinterpret_cast<const float2*>(x + c * C + lane * 2);
        acc.x += v * xv.x;
        acc.y += v * xv.y;
    }
    float* yp = y + row * C + lane * 2;
    if (COMBINE) {
        float2 p = *reinterpret_cast<const float2*>(xm2 + row * C + lane * 2);
        acc.x = 2.0f * acc.x - p.x;
        acc.y = 2.0f * acc.y - p.y;
    }
    *reinterpret_cast<float2*>(yp) = acc;
}

// ---------------------------------------------------------------------------
// FUSED output contraction: reads all 5 cheb buffers once, writes out once.
// out[(b*V+v)*64 + o] = bias[o] + sum_{fin,k} xk[v*128+fin*4+b] * w[(fin*5+k)*64+o]
__global__ __launch_bounds__(256) void fused_out(
    const float* __restrict__ x0, const float* __restrict__ x1,
    const float* __restrict__ x2, const float* __restrict__ x3,
    const float* __restrict__ x4, const float* __restrict__ w,
    const float* __restrict__ bias, float* __restrict__ out, int nblocks) {
    __shared__ float lw[K * FIN * FOUT];   // 40 KB
    __shared__ float lx[WPB][VPW * C];     // 8 KB
    const int tid = threadIdx.x;
    for (int i = tid; i < K * FIN * FOUT; i += 256) lw[i] = w[i];
    __syncthreads();
    const int lane = tid & 63;
    const int wid = tid >> 6;
    const float bs = bias[lane];
    const float* xs[K] = {x0, x1, x2, x3, x4};
    const int ngroups = V / VPW;  // 49152
    const int nw = nblocks * WPB;
    for (int g = blockIdx.x * WPB + wid; g < ngroups; g += nw) {
        const int v0 = g * VPW;
        float acc[VPW][B];
#pragma unroll
        for (int i = 0; i < VPW; ++i)
#pragma unroll
            for (int b = 0; b < B; ++b) acc[i][b] = bs;
#pragma unroll
        for (int k = 0; k < K; ++k) {
            // stage x_k rows for the VPW vertices (same-wave LDS, no barrier)
#pragma unroll
            for (int i = 0; i < VPW; ++i) {
                float2 xv = *reinterpret_cast<const float2*>(
                    xs[k] + (size_t)(v0 + i) * C + lane * 2);
                *reinterpret_cast<float2*>(&lx[wid][i * C + lane * 2]) = xv;
            }
#pragma unroll
            for (int fin = 0; fin < FIN; ++fin) {
                float wv = lw[(fin * K + k) * FOUT + lane];
#pragma unroll
                for (int i = 0; i < VPW; ++i) {
                    const float4 xq =
                        *reinterpret_cast<const float4*>(&lx[wid][i * C + fin * 4]);
                    acc[i][0] += xq.x * wv;
                    acc[i][1] += xq.y * wv;
                    acc[i][2] += xq.z * wv;
                    acc[i][3] += xq.w * wv;
                }
            }
        }
#pragma unroll
        for (int i = 0; i < VPW; ++i)
#pragma unroll
            for (int b = 0; b < B; ++b)
                out[((size_t)(b * V + v0 + i)) * FOUT + lane] = acc[i][b];
    }
}

// ---------------------------------------------------------------------------
// fallback per-k accumulation (used only if ws is too small for 5 buffers)
template <int FIRST>
__global__ void accum_term4(const float* __restrict__ xk, const float* __restrict__ w,
                            const float* __restrict__ bias, float* __restrict__ out, int k) {
    int idx = blockIdx.x * 256 + threadIdx.x;
    int o = idx & 63;
    int g = idx >> 6;
    int v = (g % (V / 4)) * 4;
    int b = g / (V / 4);
    const float* xr = xk + v * C + b;
    size_t obase = ((size_t)(b * V + v)) * 64 + o;
    float a0, a1, a2, a3;
    if (FIRST) {
        float bs = bias[o];
        a0 = a1 = a2 = a3 = bs;
    } else {
        a0 = out[obase];
        a1 = out[obase + 64];
        a2 = out[obase + 128];
        a3 = out[obase + 192];
    }
    const float* wr = w + k * 64 + o;
#pragma unroll
    for (int fin = 0; fin < FIN; ++fin) {
        float wv = wr[fin * 5 * 64];
        a0 += xr[fin * 4] * wv;
        a1 += xr[fin * 4 + 128] * wv;
        a2 += xr[fin * 4 + 256] * wv;
        a3 += xr[fin * 4 + 384] * wv;
    }
    out[obase] = a0;
    out[obase + 64] = a1;
    out[obase + 128] = a2;
    out[obase + 192] = a3;
}

// ---------------------------------------------------------------------------
extern "C" void kernel_launch(void* const* d_in, const int* in_sizes, int n_in,
                              void* d_out, int out_size, void* d_ws, size_t ws_size,
                              hipStream_t stream) {
    const int* lap_rows = (const int*)d_in[0];
    const int* lap_cols = (const int*)d_in[1];
    const float* lap_vals = (const float*)d_in[2];
    const float* inputs = (const float*)d_in[3];
    const float* weight = (const float*)d_in[4];  // flat [160][64] == effective W
    const float* bias = (const float*)d_in[5];
    float* out = (float*)d_out;

    char* p = (char*)d_ws;
    auto alloc = [&](size_t bytes) {
        char* r = p;
        p += (bytes + 511) & ~(size_t)511;
        return r;
    };
    int* rowptr = (int*)alloc((size_t)(V + 1) * 4);
    int* cursor = (int*)alloc((size_t)V * 4);
    int* ccol = (int*)alloc((size_t)NNZ * 4);
    float* cval = (float*)alloc((size_t)NNZ * 4);
    float* cb0 = (float*)alloc((size_t)XELEMS * 4);
    float* cb1 = (float*)alloc((size_t)XELEMS * 4);
    float* cb2 = (float*)alloc((size_t)XELEMS * 4);
    size_t used3 = (size_t)(p - (char*)d_ws);
    float* cb3 = (float*)alloc((size_t)XELEMS * 4);
    float* cb4 = (float*)alloc((size_t)XELEMS * 4);
    size_t used5 = (size_t)(p - (char*)d_ws);
    const bool big = (ws_size >= used5);

    const int edge_blocks = (NNZ + 255) / 256;
    const int elem_blocks = (XELEMS + 255) / 256;
    const int spmm_blocks = (V * 64 + 255) / 256;
    const int acc_blocks = (B * (V / 4) * 64) / 256;

    // ---- CSR build ----
    hipMemsetAsync(cursor, 0, (size_t)V * 4, stream);
    hist_rows<<<edge_blocks, 256, 0, stream>>>(lap_rows, cursor);
    scan_counts<<<1, 1024, 0, stream>>>(cursor, rowptr, cursor);
    scatter_edges<<<edge_blocks, 256, 0, stream>>>(lap_rows, lap_cols, lap_vals, cursor, ccol, cval);

    // ---- x0 ----
    build_x0<<<elem_blocks, 256, 0, stream>>>(inputs, cb0);

    if (big) {
        // all 5 cheb buffers, single fused output pass
        spmm_gather<0><<<spmm_blocks, 256, 0, stream>>>(rowptr, ccol, cval, cb0, nullptr, cb1);
        spmm_gather<1><<<spmm_blocks, 256, 0, stream>>>(rowptr, ccol, cval, cb1, cb0, cb2);
        spmm_gather<1><<<spmm_blocks, 256, 0, stream>>>(rowptr, ccol, cval, cb2, cb1, cb3);
        spmm_gather<1><<<spmm_blocks, 256, 0, stream>>>(rowptr, ccol, cval, cb3, cb2, cb4);
        const int nblocks = 2048;
        fused_out<<<nblocks, 256, 0, stream>>>(cb0, cb1, cb2, cb3, cb4, weight, bias, out,
                                               nblocks);
    } else {
        // fallback: 3 rotating buffers + per-k accumulation
        (void)used3;
        accum_term4<1><<<acc_blocks, 256, 0, stream>>>(cb0, weight, bias, out, 0);
        spmm_gather<0><<<spmm_blocks, 256, 0, stream>>>(rowptr, ccol, cval, cb0, nullptr, cb1);
        accum_term4<0><<<acc_blocks, 256, 0, stream>>>(cb1, weight, bias, out, 1);
        spmm_gather<1><<<spmm_blocks, 256, 0, stream>>>(rowptr, ccol, cval, cb1, cb0, cb2);
        accum_term4<0><<<acc_blocks, 256, 0, stream>>>(cb2, weight, bias, out, 2);
        spmm_gather<1><<<spmm_blocks, 256, 0, stream>>>(rowptr, ccol, cval, cb2, cb1, cb0);
        accum_term4<0><<<acc_blocks, 256, 0, stream>>>(cb0, weight, bias, out, 3);
        spmm_gather<1><<<spmm_blocks, 256, 0, stream>>>(rowptr, ccol, cval, cb0, cb2, cb1);
        accum_term4<0><<<acc_blocks, 256, 0, stream>>>(cb1, weight, bias, out, 4);
    }
}

// Round 4
// 1147.499 us; speedup vs baseline: 7.0421x; 1.7358x over previous
//
#include <hip/hip_runtime.h>
#include <hip/hip_bf16.h>

#define V 196608
#define NNZ (9 * V)
#define B 4
#define FIN 32
#define FOUT 64
#define K 5
#define C 128           // FIN*B feature columns per vertex
#define XELEMS (V * C)  // 25,165,824 floats per cheb buffer
#define VPW 8           // vertices per wave in fused_out

// ---------------------------------------------------------------------------
// x0[v*128 + fin*4 + b] = inputs[(b*V + v)*32 + fin]
__global__ void build_x0(const float* __restrict__ inp, float* __restrict__ x0) {
    int idx = blockIdx.x * 256 + threadIdx.x;
    if (idx >= XELEMS) return;
    int c = idx & (C - 1);
    int v = idx >> 7;
    int fin = c >> 2;
    int b = c & 3;
    x0[idx] = inp[((b * V + v) << 5) + fin];
}

// ---------------------------------------------------------------------------
// CSR build step 1: histogram row counts into cnt[] (pre-zeroed)
__global__ void hist_rows(const int* __restrict__ rows, int* __restrict__ cnt) {
    int e = blockIdx.x * 256 + threadIdx.x;
    if (e < NNZ) atomicAdd(&cnt[rows[e]], 1);
}

// ---------------------------------------------------------------------------
// parallel scan phase A: per-1024-chunk sums (192 blocks x 1024 threads)
__global__ void chunk_sums(const int* __restrict__ cnt, int* __restrict__ bsum) {
    __shared__ int ws[16];
    int tid = threadIdx.x;
    int lane = tid & 63;
    int wid = tid >> 6;
    int v = cnt[blockIdx.x * 1024 + tid];
#pragma unroll
    for (int off = 32; off >= 1; off >>= 1) v += __shfl_down(v, off, 64);
    if (lane == 0) ws[wid] = v;
    __syncthreads();
    if (tid < 16) {
        int s = ws[tid];
#pragma unroll
        for (int off = 8; off >= 1; off >>= 1) s += __shfl_down(s, off, 16);
        if (tid == 0) bsum[blockIdx.x] = s;
    }
}

// ---------------------------------------------------------------------------
// parallel scan phase B: exclusive scan of 192 chunk sums (1 block, 256 thr)
__global__ void scan_sums(const int* __restrict__ bsum, int* __restrict__ bpre,
                          int* __restrict__ rowptr) {
    __shared__ int ws[4];
    int tid = threadIdx.x;
    int lane = tid & 63;
    int wid = tid >> 6;
    int v = (tid < 192) ? bsum[tid] : 0;
    int x = v;
#pragma unroll
    for (int off = 1; off < 64; off <<= 1) {
        int t = __shfl_up(x, off, 64);
        if (lane >= off) x += t;
    }
    if (lane == 63) ws[wid] = x;
    __syncthreads();
    if (wid == 0 && lane < 4) {
        int s = ws[lane];
        int y = s;
#pragma unroll
        for (int off = 1; off < 4; off <<= 1) {
            int t = __shfl_up(y, off, 4);
            if (lane >= off) y += t;
        }
        ws[lane] = y - s;
    }
    __syncthreads();
    int incl = x + ws[wid];
    if (tid < 192) bpre[tid] = incl - v;
    if (tid == 191) rowptr[V] = incl;
}

// ---------------------------------------------------------------------------
// parallel scan phase C: per-chunk scan + chunk prefix (192 blocks x 1024)
__global__ void scan_chunks(const int* __restrict__ cnt, const int* __restrict__ bpre,
                            int* __restrict__ rowptr, int* __restrict__ cursor) {
    __shared__ int wsum[16];
    int tid = threadIdx.x;
    int lane = tid & 63;
    int wid = tid >> 6;
    int base = blockIdx.x * 1024;
    int v = cnt[base + tid];
    int x = v;
#pragma unroll
    for (int off = 1; off < 64; off <<= 1) {
        int t = __shfl_up(x, off, 64);
        if (lane >= off) x += t;
    }
    if (lane == 63) wsum[wid] = x;
    __syncthreads();
    if (wid == 0 && lane < 16) {
        int s = wsum[lane];
        int y = s;
#pragma unroll
        for (int off = 1; off < 16; off <<= 1) {
            int t = __shfl_up(y, off, 16);
            if (lane >= off) y += t;
        }
        wsum[lane] = y - s;
    }
    __syncthreads();
    int excl = x - v + wsum[wid] + bpre[blockIdx.x];
    rowptr[base + tid] = excl;
    cursor[base + tid] = excl;
}

// ---------------------------------------------------------------------------
// CSR build: scatter edges into row-grouped order
__global__ void scatter_edges(const int* __restrict__ rows, const int* __restrict__ cols,
                              const float* __restrict__ vals, int* __restrict__ cursor,
                              int* __restrict__ ccol, float* __restrict__ cval) {
    int e = blockIdx.x * 256 + threadIdx.x;
    if (e >= NNZ) return;
    int r = rows[e];
    int p = atomicAdd(&cursor[r], 1);
    ccol[p] = cols[e];
    cval[p] = vals[e];
}

// ---------------------------------------------------------------------------
// gather SpMM, strip-mined x4 for memory-level parallelism.
// y[r] = sum_e val_e * x[col_e]           (COMBINE=0)
// y[r] = 2*sum - xm2[r]                   (COMBINE=1)
template <int COMBINE>
__global__ void spmm_gather(const int* __restrict__ rowptr, const int* __restrict__ ccol,
                            const float* __restrict__ cval, const float* __restrict__ x,
                            const float* __restrict__ xm2, float* __restrict__ y) {
    int row = (blockIdx.x * 256 + threadIdx.x) >> 6;
    int lane = threadIdx.x & 63;
    if (row >= V) return;
    int s = rowptr[row];
    int e = rowptr[row + 1];
    const float* xl = x + lane * 2;
    float2 acc = {0.0f, 0.0f};
    int i = s;
    int e4 = s + ((e - s) & ~3);
    for (; i < e4; i += 4) {
        int c0 = ccol[i], c1 = ccol[i + 1], c2 = ccol[i + 2], c3 = ccol[i + 3];
        float v0 = cval[i], v1 = cval[i + 1], v2 = cval[i + 2], v3 = cval[i + 3];
        float2 a0 = *reinterpret_cast<const float2*>(xl + (size_t)c0 * C);
        float2 a1 = *reinterpret_cast<const float2*>(xl + (size_t)c1 * C);
        float2 a2 = *reinterpret_cast<const float2*>(xl + (size_t)c2 * C);
        float2 a3 = *reinterpret_cast<const float2*>(xl + (size_t)c3 * C);
        acc.x = fmaf(v0, a0.x, acc.x);
        acc.y = fmaf(v0, a0.y, acc.y);
        acc.x = fmaf(v1, a1.x, acc.x);
        acc.y = fmaf(v1, a1.y, acc.y);
        acc.x = fmaf(v2, a2.x, acc.x);
        acc.y = fmaf(v2, a2.y, acc.y);
        acc.x = fmaf(v3, a3.x, acc.x);
        acc.y = fmaf(v3, a3.y, acc.y);
    }
    for (; i < e; ++i) {
        int c = ccol[i];
        float v = cval[i];
        float2 a = *reinterpret_cast<const float2*>(xl + (size_t)c * C);
        acc.x = fmaf(v, a.x, acc.x);
        acc.y = fmaf(v, a.y, acc.y);
    }
    float* yp = y + (size_t)row * C + lane * 2;
    if (COMBINE) {
        float2 p = *reinterpret_cast<const float2*>(xm2 + (size_t)row * C + lane * 2);
        acc.x = 2.0f * acc.x - p.x;
        acc.y = 2.0f * acc.y - p.y;
    }
    *reinterpret_cast<float2*>(yp) = acc;
}

// ---------------------------------------------------------------------------
// FUSED output contraction v2: no barriers, per-wave LDS x-stage, W from L1.
// wave g handles vertices v0..v0+7, lane = o.
// out[(b*V+v)*64 + o] = bias[o] + sum_{k,fin} xk[v*128+fin*4+b] * w[(fin*5+k)*64+o]
__global__ __launch_bounds__(256) void fused_out(
    const float* __restrict__ x0, const float* __restrict__ x1,
    const float* __restrict__ x2, const float* __restrict__ x3,
    const float* __restrict__ x4, const float* __restrict__ w,
    const float* __restrict__ bias, float* __restrict__ out) {
    __shared__ float lx[4][VPW * C];  // 16 KB, one 4KB slab per wave
    const int tid = threadIdx.x;
    const int lane = tid & 63;
    const int wid = tid >> 6;
    const int g = (blockIdx.x * 256 + tid) >> 6;  // wave id == vertex group
    if (g >= V / VPW) return;
    const int v0 = g * VPW;
    const float bs = bias[lane];
    float acc[VPW][B];
#pragma unroll
    for (int i = 0; i < VPW; ++i)
#pragma unroll
        for (int b = 0; b < B; ++b) acc[i][b] = bs;

    const float* const xs[K] = {x0, x1, x2, x3, x4};
    float4* const slab = reinterpret_cast<float4*>(&lx[wid][0]);
#pragma unroll
    for (int k = 0; k < K; ++k) {
        // stage the 8 x-rows (4 KB) for this wave: coalesced global float4
        const float4* src = reinterpret_cast<const float4*>(xs[k] + (size_t)v0 * C);
#pragma unroll
        for (int t = 0; t < (VPW * C / 4) / 64; ++t) {  // 4 float4 per lane
            slab[lane + t * 64] = src[lane + t * 64];
        }
        const float* wk = w + k * FOUT + lane;
        for (int fin = 0; fin < FIN; ++fin) {
            float wv = wk[fin * (K * FOUT)];  // per-lane, L1-hot (8KB slice)
#pragma unroll
            for (int i = 0; i < VPW; ++i) {
                float4 xq = slab[i * (C / 4) + fin];  // uniform broadcast read
                acc[i][0] = fmaf(xq.x, wv, acc[i][0]);
                acc[i][1] = fmaf(xq.y, wv, acc[i][1]);
                acc[i][2] = fmaf(xq.z, wv, acc[i][2]);
                acc[i][3] = fmaf(xq.w, wv, acc[i][3]);
            }
        }
    }
#pragma unroll
    for (int i = 0; i < VPW; ++i)
#pragma unroll
        for (int b = 0; b < B; ++b)
            out[((size_t)b * V + v0 + i) * FOUT + lane] = acc[i][b];
}

// ---------------------------------------------------------------------------
// fallback per-k accumulation (used only if ws is too small for 5 buffers)
template <int FIRST>
__global__ void accum_term4(const float* __restrict__ xk, const float* __restrict__ w,
                            const float* __restrict__ bias, float* __restrict__ out, int k) {
    int idx = blockIdx.x * 256 + threadIdx.x;
    int o = idx & 63;
    int g = idx >> 6;
    int v = (g % (V / 4)) * 4;
    int b = g / (V / 4);
    const float* xr = xk + v * C + b;
    size_t obase = ((size_t)(b * V + v)) * 64 + o;
    float a0, a1, a2, a3;
    if (FIRST) {
        float bs = bias[o];
        a0 = a1 = a2 = a3 = bs;
    } else {
        a0 = out[obase];
        a1 = out[obase + 64];
        a2 = out[obase + 128];
        a3 = out[obase + 192];
    }
    const float* wr = w + k * 64 + o;
#pragma unroll
    for (int fin = 0; fin < FIN; ++fin) {
        float wv = wr[fin * 5 * 64];
        a0 += xr[fin * 4] * wv;
        a1 += xr[fin * 4 + 128] * wv;
        a2 += xr[fin * 4 + 256] * wv;
        a3 += xr[fin * 4 + 384] * wv;
    }
    out[obase] = a0;
    out[obase + 64] = a1;
    out[obase + 128] = a2;
    out[obase + 192] = a3;
}

// ---------------------------------------------------------------------------
extern "C" void kernel_launch(void* const* d_in, const int* in_sizes, int n_in,
                              void* d_out, int out_size, void* d_ws, size_t ws_size,
                              hipStream_t stream) {
    const int* lap_rows = (const int*)d_in[0];
    const int* lap_cols = (const int*)d_in[1];
    const float* lap_vals = (const float*)d_in[2];
    const float* inputs = (const float*)d_in[3];
    const float* weight = (const float*)d_in[4];  // flat [160][64] == effective W
    const float* bias = (const float*)d_in[5];
    float* out = (float*)d_out;

    char* p = (char*)d_ws;
    auto alloc = [&](size_t bytes) {
        char* r = p;
        p += (bytes + 511) & ~(size_t)511;
        return r;
    };
    int* rowptr = (int*)alloc((size_t)(V + 1) * 4);
    int* cursor = (int*)alloc((size_t)V * 4);
    int* bsum = (int*)alloc(192 * 4);
    int* bpre = (int*)alloc(192 * 4);
    int* ccol = (int*)alloc((size_t)NNZ * 4);
    float* cval = (float*)alloc((size_t)NNZ * 4);
    float* cb0 = (float*)alloc((size_t)XELEMS * 4);
    float* cb1 = (float*)alloc((size_t)XELEMS * 4);
    float* cb2 = (float*)alloc((size_t)XELEMS * 4);
    float* cb3 = (float*)alloc((size_t)XELEMS * 4);
    float* cb4 = (float*)alloc((size_t)XELEMS * 4);
    size_t used5 = (size_t)(p - (char*)d_ws);
    const bool big = (ws_size >= used5);

    const int edge_blocks = (NNZ + 255) / 256;
    const int elem_blocks = (XELEMS + 255) / 256;
    const int spmm_blocks = (V * 64 + 255) / 256;
    const int acc_blocks = (B * (V / 4) * 64) / 256;
    const int fused_blocks = (V / VPW) / 4;  // 1 wave per 8-vertex group

    // ---- CSR build ----
    hipMemsetAsync(cursor, 0, (size_t)V * 4, stream);
    hist_rows<<<edge_blocks, 256, 0, stream>>>(lap_rows, cursor);
    chunk_sums<<<V / 1024, 1024, 0, stream>>>(cursor, bsum);
    scan_sums<<<1, 256, 0, stream>>>(bsum, bpre, rowptr);
    scan_chunks<<<V / 1024, 1024, 0, stream>>>(cursor, bpre, rowptr, cursor);
    scatter_edges<<<edge_blocks, 256, 0, stream>>>(lap_rows, lap_cols, lap_vals, cursor, ccol, cval);

    // ---- x0 ----
    build_x0<<<elem_blocks, 256, 0, stream>>>(inputs, cb0);

    if (big) {
        spmm_gather<0><<<spmm_blocks, 256, 0, stream>>>(rowptr, ccol, cval, cb0, nullptr, cb1);
        spmm_gather<1><<<spmm_blocks, 256, 0, stream>>>(rowptr, ccol, cval, cb1, cb0, cb2);
        spmm_gather<1><<<spmm_blocks, 256, 0, stream>>>(rowptr, ccol, cval, cb2, cb1, cb3);
        spmm_gather<1><<<spmm_blocks, 256, 0, stream>>>(rowptr, ccol, cval, cb3, cb2, cb4);
        fused_out<<<fused_blocks, 256, 0, stream>>>(cb0, cb1, cb2, cb3, cb4, weight, bias, out);
    } else {
        accum_term4<1><<<acc_blocks, 256, 0, stream>>>(cb0, weight, bias, out, 0);
        spmm_gather<0><<<spmm_blocks, 256, 0, stream>>>(rowptr, ccol, cval, cb0, nullptr, cb1);
        accum_term4<0><<<acc_blocks, 256, 0, stream>>>(cb1, weight, bias, out, 1);
        spmm_gather<1><<<spmm_blocks, 256, 0, stream>>>(rowptr, ccol, cval, cb1, cb0, cb2);
        accum_term4<0><<<acc_blocks, 256, 0, stream>>>(cb2, weight, bias, out, 2);
        spmm_gather<1><<<spmm_blocks, 256, 0, stream>>>(rowptr, ccol, cval, cb2, cb1, cb0);
        accum_term4<0><<<acc_blocks, 256, 0, stream>>>(cb0, weight, bias, out, 3);
        spmm_gather<1><<<spmm_blocks, 256, 0, stream>>>(rowptr, ccol, cval, cb0, cb2, cb1);
        accum_term4<0><<<acc_blocks, 256, 0, stream>>>(cb1, weight, bias, out, 4);
    }
}

// Round 5
// 917.474 us; speedup vs baseline: 8.8077x; 1.2507x over previous
//
#include <hip/hip_runtime.h>

#define V 196608
#define NNZ (9 * V)
#define B 4
#define FIN 32
#define FOUT 64
#define K 5
#define C 128            // FIN*B feature columns per vertex
#define ROWU 64          // uints per bf16 row (128 feats * 2B / 4B)
#define VPW 8            // vertices per wave in fused_out

// ---- bf16 helpers (bit-level, RNE) ---------------------------------------
static __device__ __forceinline__ unsigned int f2bf(float f) {
    union { float f; unsigned int u; } v; v.f = f;
    return (v.u + 0x7FFFu + ((v.u >> 16) & 1u)) >> 16;
}
static __device__ __forceinline__ float bflo(unsigned int u) {
    union { unsigned int u; float f; } v; v.u = u << 16; return v.f;
}
static __device__ __forceinline__ float bfhi(unsigned int u) {
    union { unsigned int u; float f; } v; v.u = u & 0xFFFF0000u; return v.f;
}

// ---------------------------------------------------------------------------
// x0[v][fin*4+b] (bf16) = inputs[(b*V+v)*32+fin]; one thread per (v,fin)
__global__ void build_x0(const float* __restrict__ inp, unsigned int* __restrict__ x0) {
    int t = blockIdx.x * 256 + threadIdx.x;
    if (t >= V * FIN) return;
    int fin = t & 31;
    int v = t >> 5;
    const size_t plane = (size_t)V * FIN;
    const float* s = inp + ((size_t)v << 5) + fin;
    float b0 = s[0];
    float b1 = s[plane];
    float b2 = s[2 * plane];
    float b3 = s[3 * plane];
    uint2 u;
    u.x = f2bf(b0) | (f2bf(b1) << 16);
    u.y = f2bf(b2) | (f2bf(b3) << 16);
    reinterpret_cast<uint2*>(x0)[(size_t)v * 32 + fin] = u;
}

// ---------------------------------------------------------------------------
// CSR build step 1: histogram row counts into cnt[] (pre-zeroed)
__global__ void hist_rows(const int* __restrict__ rows, int* __restrict__ cnt) {
    int e = blockIdx.x * 256 + threadIdx.x;
    if (e < NNZ) atomicAdd(&cnt[rows[e]], 1);
}

// ---------------------------------------------------------------------------
// parallel scan phase A: per-1024-chunk sums
__global__ void chunk_sums(const int* __restrict__ cnt, int* __restrict__ bsum) {
    __shared__ int ws[16];
    int tid = threadIdx.x;
    int lane = tid & 63;
    int wid = tid >> 6;
    int v = cnt[blockIdx.x * 1024 + tid];
#pragma unroll
    for (int off = 32; off >= 1; off >>= 1) v += __shfl_down(v, off, 64);
    if (lane == 0) ws[wid] = v;
    __syncthreads();
    if (tid < 16) {
        int s = ws[tid];
#pragma unroll
        for (int off = 8; off >= 1; off >>= 1) s += __shfl_down(s, off, 16);
        if (tid == 0) bsum[blockIdx.x] = s;
    }
}

// ---------------------------------------------------------------------------
// parallel scan phase B: exclusive scan of 192 chunk sums
__global__ void scan_sums(const int* __restrict__ bsum, int* __restrict__ bpre,
                          int* __restrict__ rowptr) {
    __shared__ int ws[4];
    int tid = threadIdx.x;
    int lane = tid & 63;
    int wid = tid >> 6;
    int v = (tid < 192) ? bsum[tid] : 0;
    int x = v;
#pragma unroll
    for (int off = 1; off < 64; off <<= 1) {
        int t = __shfl_up(x, off, 64);
        if (lane >= off) x += t;
    }
    if (lane == 63) ws[wid] = x;
    __syncthreads();
    if (wid == 0 && lane < 4) {
        int s = ws[lane];
        int y = s;
#pragma unroll
        for (int off = 1; off < 4; off <<= 1) {
            int t = __shfl_up(y, off, 4);
            if (lane >= off) y += t;
        }
        ws[lane] = y - s;
    }
    __syncthreads();
    int incl = x + ws[wid];
    if (tid < 192) bpre[tid] = incl - v;
    if (tid == 191) rowptr[V] = incl;
}

// ---------------------------------------------------------------------------
// parallel scan phase C: per-chunk scan + chunk prefix
__global__ void scan_chunks(const int* __restrict__ cnt, const int* __restrict__ bpre,
                            int* __restrict__ rowptr, int* __restrict__ cursor) {
    __shared__ int wsum[16];
    int tid = threadIdx.x;
    int lane = tid & 63;
    int wid = tid >> 6;
    int base = blockIdx.x * 1024;
    int v = cnt[base + tid];
    int x = v;
#pragma unroll
    for (int off = 1; off < 64; off <<= 1) {
        int t = __shfl_up(x, off, 64);
        if (lane >= off) x += t;
    }
    if (lane == 63) wsum[wid] = x;
    __syncthreads();
    if (wid == 0 && lane < 16) {
        int s = wsum[lane];
        int y = s;
#pragma unroll
        for (int off = 1; off < 16; off <<= 1) {
            int t = __shfl_up(y, off, 16);
            if (lane >= off) y += t;
        }
        wsum[lane] = y - s;
    }
    __syncthreads();
    int excl = x - v + wsum[wid] + bpre[blockIdx.x];
    rowptr[base + tid] = excl;
    cursor[base + tid] = excl;
}

// ---------------------------------------------------------------------------
// CSR build: scatter edges, packed (col, val) int2 single 8B write
__global__ void scatter_edges(const int* __restrict__ rows, const int* __restrict__ cols,
                              const float* __restrict__ vals, int* __restrict__ cursor,
                              int2* __restrict__ cev) {
    int e = blockIdx.x * 256 + threadIdx.x;
    if (e >= NNZ) return;
    int r = rows[e];
    int p = atomicAdd(&cursor[r], 1);
    int2 pk;
    pk.x = cols[e];
    pk.y = __float_as_int(vals[e]);
    cev[p] = pk;
}

// ---------------------------------------------------------------------------
// bf16 gather SpMM: wave per row, lane owns features 2*lane, 2*lane+1.
// y[r] = sum val * x[col]          (COMBINE=0)
// y[r] = 2*sum - xm2[r]            (COMBINE=1)
template <int COMBINE>
__global__ void spmm_gather(const int* __restrict__ rowptr, const int2* __restrict__ cev,
                            const unsigned int* __restrict__ x,
                            const unsigned int* __restrict__ xm2,
                            unsigned int* __restrict__ y) {
    int row = (blockIdx.x * 256 + threadIdx.x) >> 6;
    int lane = threadIdx.x & 63;
    if (row >= V) return;
    int s = rowptr[row];
    int e = rowptr[row + 1];
    float ax = 0.0f, ay = 0.0f;
    int i = s;
    int e4 = s + ((e - s) & ~3);
    for (; i < e4; i += 4) {
        int2 e0 = cev[i], e1 = cev[i + 1], e2 = cev[i + 2], e3 = cev[i + 3];
        unsigned int u0 = x[(size_t)e0.x * ROWU + lane];
        unsigned int u1 = x[(size_t)e1.x * ROWU + lane];
        unsigned int u2 = x[(size_t)e2.x * ROWU + lane];
        unsigned int u3 = x[(size_t)e3.x * ROWU + lane];
        float v0 = __int_as_float(e0.y), v1 = __int_as_float(e1.y);
        float v2 = __int_as_float(e2.y), v3 = __int_as_float(e3.y);
        ax = fmaf(v0, bflo(u0), ax);
        ay = fmaf(v0, bfhi(u0), ay);
        ax = fmaf(v1, bflo(u1), ax);
        ay = fmaf(v1, bfhi(u1), ay);
        ax = fmaf(v2, bflo(u2), ax);
        ay = fmaf(v2, bfhi(u2), ay);
        ax = fmaf(v3, bflo(u3), ax);
        ay = fmaf(v3, bfhi(u3), ay);
    }
    for (; i < e; ++i) {
        int2 ee = cev[i];
        unsigned int u = x[(size_t)ee.x * ROWU + lane];
        float v = __int_as_float(ee.y);
        ax = fmaf(v, bflo(u), ax);
        ay = fmaf(v, bfhi(u), ay);
    }
    if (COMBINE) {
        unsigned int m = xm2[(size_t)row * ROWU + lane];
        ax = 2.0f * ax - bflo(m);
        ay = 2.0f * ay - bfhi(m);
    }
    y[(size_t)row * ROWU + lane] = f2bf(ax) | (f2bf(ay) << 16);
}

// ---------------------------------------------------------------------------
// FUSED output contraction v3: bf16 cheb in, f32 slab in LDS (converted at
// stage time), register prefetch of next k's rows, no barriers.
// out[(b*V+v)*64+o] = bias[o] + sum_{k,fin} x_k[v][fin*4+b] * w[(fin*5+k)*64+o]
__global__ __launch_bounds__(256) void fused_out(
    const unsigned int* __restrict__ x0, const unsigned int* __restrict__ x1,
    const unsigned int* __restrict__ x2, const unsigned int* __restrict__ x3,
    const unsigned int* __restrict__ x4, const float* __restrict__ w,
    const float* __restrict__ bias, float* __restrict__ out) {
    __shared__ float lx[4][VPW * C];  // 16 KB, 4 KB slab per wave
    const int tid = threadIdx.x;
    const int lane = tid & 63;
    const int wid = tid >> 6;
    const int g = (blockIdx.x * 256 + tid) >> 6;
    if (g >= V / VPW) return;
    const int v0 = g * VPW;
    const float bs = bias[lane];
    float acc[VPW][B];
#pragma unroll
    for (int i = 0; i < VPW; ++i)
#pragma unroll
        for (int b = 0; b < B; ++b) acc[i][b] = bs;

    const unsigned int* const xs[K] = {x0, x1, x2, x3, x4};
    float* const slab = &lx[wid][0];

    // chunk geometry: 8 rows * 64 uints = 128 uint4 chunks; lane owns chunks
    // {lane, lane+64}; chunk c covers flat features [c*8, c*8+8) -> row c>>4,
    // in-row offset (c&15)*8.
    const int c0 = lane, c1 = lane + 64;
    const int r0 = c0 >> 4, f0 = (c0 & 15) * 8;
    const int r1 = c1 >> 4, f1 = (c1 & 15) * 8;

    const uint4* src = reinterpret_cast<const uint4*>(xs[0] + (size_t)v0 * ROWU);
    uint4 pa = src[c0];
    uint4 pb = src[c1];
#pragma unroll
    for (int k = 0; k < K; ++k) {
        uint4 ca = pa, cb = pb;
        if (k < K - 1) {
            const uint4* nsrc = reinterpret_cast<const uint4*>(xs[k + 1] + (size_t)v0 * ROWU);
            pa = nsrc[c0];
            pb = nsrc[c1];
        }
        // stage (convert bf16 -> f32) into this wave's slab
        float4 wa0 = {bflo(ca.x), bfhi(ca.x), bflo(ca.y), bfhi(ca.y)};
        float4 wa1 = {bflo(ca.z), bfhi(ca.z), bflo(ca.w), bfhi(ca.w)};
        float4 wb0 = {bflo(cb.x), bfhi(cb.x), bflo(cb.y), bfhi(cb.y)};
        float4 wb1 = {bflo(cb.z), bfhi(cb.z), bflo(cb.w), bfhi(cb.w)};
        *reinterpret_cast<float4*>(&slab[r0 * C + f0]) = wa0;
        *reinterpret_cast<float4*>(&slab[r0 * C + f0 + 4]) = wa1;
        *reinterpret_cast<float4*>(&slab[r1 * C + f1]) = wb0;
        *reinterpret_cast<float4*>(&slab[r1 * C + f1 + 4]) = wb1;
        // same-wave produce->consume: compiler inserts lgkmcnt, no barrier
        const float* wk = w + k * FOUT + lane;
        for (int fin = 0; fin < FIN; ++fin) {
            float wv = wk[fin * (K * FOUT)];  // per-lane, L1/L2-hot
#pragma unroll
            for (int i = 0; i < VPW; ++i) {
                float4 xq = *reinterpret_cast<const float4*>(&slab[i * C + fin * 4]);
                acc[i][0] = fmaf(xq.x, wv, acc[i][0]);
                acc[i][1] = fmaf(xq.y, wv, acc[i][1]);
                acc[i][2] = fmaf(xq.z, wv, acc[i][2]);
                acc[i][3] = fmaf(xq.w, wv, acc[i][3]);
            }
        }
    }
#pragma unroll
    for (int i = 0; i < VPW; ++i)
#pragma unroll
        for (int b = 0; b < B; ++b)
            out[((size_t)b * V + v0 + i) * FOUT + lane] = acc[i][b];
}

// ---------------------------------------------------------------------------
extern "C" void kernel_launch(void* const* d_in, const int* in_sizes, int n_in,
                              void* d_out, int out_size, void* d_ws, size_t ws_size,
                              hipStream_t stream) {
    const int* lap_rows = (const int*)d_in[0];
    const int* lap_cols = (const int*)d_in[1];
    const float* lap_vals = (const float*)d_in[2];
    const float* inputs = (const float*)d_in[3];
    const float* weight = (const float*)d_in[4];  // flat [160][64] == effective W
    const float* bias = (const float*)d_in[5];
    float* out = (float*)d_out;

    char* p = (char*)d_ws;
    auto alloc = [&](size_t bytes) {
        char* r = p;
        p += (bytes + 511) & ~(size_t)511;
        return r;
    };
    int* rowptr = (int*)alloc((size_t)(V + 1) * 4);
    int* cursor = (int*)alloc((size_t)V * 4);
    int* bsum = (int*)alloc(192 * 4);
    int* bpre = (int*)alloc(192 * 4);
    int2* cev = (int2*)alloc((size_t)NNZ * 8);
    unsigned int* xb0 = (unsigned int*)alloc((size_t)V * ROWU * 4);
    unsigned int* xb1 = (unsigned int*)alloc((size_t)V * ROWU * 4);
    unsigned int* xb2 = (unsigned int*)alloc((size_t)V * ROWU * 4);
    unsigned int* xb3 = (unsigned int*)alloc((size_t)V * ROWU * 4);
    unsigned int* xb4 = (unsigned int*)alloc((size_t)V * ROWU * 4);

    const int edge_blocks = (NNZ + 255) / 256;
    const int x0_blocks = (V * FIN) / 256;
    const int spmm_blocks = (V * 64) / 256;
    const int fused_blocks = (V / VPW) / 4;

    // ---- CSR build ----
    hipMemsetAsync(cursor, 0, (size_t)V * 4, stream);
    hist_rows<<<edge_blocks, 256, 0, stream>>>(lap_rows, cursor);
    chunk_sums<<<V / 1024, 1024, 0, stream>>>(cursor, bsum);
    scan_sums<<<1, 256, 0, stream>>>(bsum, bpre, rowptr);
    scan_chunks<<<V / 1024, 1024, 0, stream>>>(cursor, bpre, rowptr, cursor);
    scatter_edges<<<edge_blocks, 256, 0, stream>>>(lap_rows, lap_cols, lap_vals, cursor, cev);

    // ---- x0 (bf16) ----
    build_x0<<<x0_blocks, 256, 0, stream>>>(inputs, xb0);

    // ---- Chebyshev recurrence (bf16 storage, f32 accumulate) ----
    spmm_gather<0><<<spmm_blocks, 256, 0, stream>>>(rowptr, cev, xb0, nullptr, xb1);
    spmm_gather<1><<<spmm_blocks, 256, 0, stream>>>(rowptr, cev, xb1, xb0, xb2);
    spmm_gather<1><<<spmm_blocks, 256, 0, stream>>>(rowptr, cev, xb2, xb1, xb3);
    spmm_gather<1><<<spmm_blocks, 256, 0, stream>>>(rowptr, cev, xb3, xb2, xb4);

    // ---- fused output contraction ----
    fused_out<<<fused_blocks, 256, 0, stream>>>(xb0, xb1, xb2, xb3, xb4, weight, bias, out);
}

// Round 6
// 747.904 us; speedup vs baseline: 10.8046x; 1.2267x over previous
//
#include <hip/hip_runtime.h>

#define V 196608
#define NNZ (9 * V)
#define B 4
#define FIN 32
#define FOUT 64
#define K 5
#define C 128            // FIN*B feature columns per vertex
#define ROWU 64          // uints per bf16 row (128 feats * 2B / 4B)

typedef __attribute__((ext_vector_type(8))) short bf16x8;
typedef __attribute__((ext_vector_type(4))) float f32x4;

// ---- bf16 helpers (bit-level, RNE) ---------------------------------------
static __device__ __forceinline__ unsigned int f2bf(float f) {
    union { float f; unsigned int u; } v; v.f = f;
    return (v.u + 0x7FFFu + ((v.u >> 16) & 1u)) >> 16;
}
static __device__ __forceinline__ float bflo(unsigned int u) {
    union { unsigned int u; float f; } v; v.u = u << 16; return v.f;
}
static __device__ __forceinline__ float bfhi(unsigned int u) {
    union { unsigned int u; float f; } v; v.u = u & 0xFFFF0000u; return v.f;
}

// ---------------------------------------------------------------------------
// x0[v][b*32+fin] (bf16, b-major row) = inputs[(b*V+v)*32+fin]
// one thread per (v, dword d): d = b*16 + fin/2
__global__ void build_x0(const float* __restrict__ inp, unsigned int* __restrict__ x0) {
    int t = blockIdx.x * 256 + threadIdx.x;
    if (t >= V * 64) return;
    int d = t & 63;
    int v = t >> 6;
    int b = d >> 4;
    int fin = (d & 15) * 2;
    const float* s = inp + ((size_t)b * V + v) * 32 + fin;
    float f0 = s[0], f1 = s[1];
    x0[(size_t)v * ROWU + d] = f2bf(f0) | (f2bf(f1) << 16);
}

// ---------------------------------------------------------------------------
// W fragment prep: split-precision bf16 B-fragments, k-major K ordering.
// wfh/wfl[(k*4+nt)*64 + lane] = 8 bf16: e -> W[((quad*8+e)*5 + k)*64 + nt*16 + col]
__global__ void build_wfrag(const float* __restrict__ w, uint4* __restrict__ wfh,
                            uint4* __restrict__ wfl) {
    int idx = blockIdx.x * 256 + threadIdx.x;
    if (idx >= K * 4 * 64) return;
    int lane = idx & 63;
    int nt = (idx >> 6) & 3;
    int k = idx >> 8;
    int col = lane & 15;
    int quad = lane >> 4;
    int o = nt * 16 + col;
    unsigned int hh[8], ll[8];
#pragma unroll
    for (int e = 0; e < 8; ++e) {
        int fin = quad * 8 + e;
        float wv = w[(fin * 5 + k) * 64 + o];
        unsigned int hb = f2bf(wv);
        float hf = bflo(hb);
        ll[e] = f2bf(wv - hf);
        hh[e] = hb;
    }
    uint4 uh, ul;
    uh.x = hh[0] | (hh[1] << 16);
    uh.y = hh[2] | (hh[3] << 16);
    uh.z = hh[4] | (hh[5] << 16);
    uh.w = hh[6] | (hh[7] << 16);
    ul.x = ll[0] | (ll[1] << 16);
    ul.y = ll[2] | (ll[3] << 16);
    ul.z = ll[4] | (ll[5] << 16);
    ul.w = ll[6] | (ll[7] << 16);
    wfh[idx] = uh;
    wfl[idx] = ul;
}

// ---------------------------------------------------------------------------
// CSR build step 1: histogram row counts into cnt[] (pre-zeroed)
__global__ void hist_rows(const int* __restrict__ rows, int* __restrict__ cnt) {
    int e = blockIdx.x * 256 + threadIdx.x;
    if (e < NNZ) atomicAdd(&cnt[rows[e]], 1);
}

// ---------------------------------------------------------------------------
// parallel scan phase A: per-1024-chunk sums
__global__ void chunk_sums(const int* __restrict__ cnt, int* __restrict__ bsum) {
    __shared__ int ws[16];
    int tid = threadIdx.x;
    int lane = tid & 63;
    int wid = tid >> 6;
    int v = cnt[blockIdx.x * 1024 + tid];
#pragma unroll
    for (int off = 32; off >= 1; off >>= 1) v += __shfl_down(v, off, 64);
    if (lane == 0) ws[wid] = v;
    __syncthreads();
    if (tid < 16) {
        int s = ws[tid];
#pragma unroll
        for (int off = 8; off >= 1; off >>= 1) s += __shfl_down(s, off, 16);
        if (tid == 0) bsum[blockIdx.x] = s;
    }
}

// ---------------------------------------------------------------------------
// parallel scan phase B: exclusive scan of 192 chunk sums
__global__ void scan_sums(const int* __restrict__ bsum, int* __restrict__ bpre,
                          int* __restrict__ rowptr) {
    __shared__ int ws[4];
    int tid = threadIdx.x;
    int lane = tid & 63;
    int wid = tid >> 6;
    int v = (tid < 192) ? bsum[tid] : 0;
    int x = v;
#pragma unroll
    for (int off = 1; off < 64; off <<= 1) {
        int t = __shfl_up(x, off, 64);
        if (lane >= off) x += t;
    }
    if (lane == 63) ws[wid] = x;
    __syncthreads();
    if (wid == 0 && lane < 4) {
        int s = ws[lane];
        int y = s;
#pragma unroll
        for (int off = 1; off < 4; off <<= 1) {
            int t = __shfl_up(y, off, 4);
            if (lane >= off) y += t;
        }
        ws[lane] = y - s;
    }
    __syncthreads();
    int incl = x + ws[wid];
    if (tid < 192) bpre[tid] = incl - v;
    if (tid == 191) rowptr[V] = incl;
}

// ---------------------------------------------------------------------------
// parallel scan phase C: per-chunk scan + chunk prefix
__global__ void scan_chunks(const int* __restrict__ cnt, const int* __restrict__ bpre,
                            int* __restrict__ rowptr, int* __restrict__ cursor) {
    __shared__ int wsum[16];
    int tid = threadIdx.x;
    int lane = tid & 63;
    int wid = tid >> 6;
    int base = blockIdx.x * 1024;
    int v = cnt[base + tid];
    int x = v;
#pragma unroll
    for (int off = 1; off < 64; off <<= 1) {
        int t = __shfl_up(x, off, 64);
        if (lane >= off) x += t;
    }
    if (lane == 63) wsum[wid] = x;
    __syncthreads();
    if (wid == 0 && lane < 16) {
        int s = wsum[lane];
        int y = s;
#pragma unroll
        for (int off = 1; off < 16; off <<= 1) {
            int t = __shfl_up(y, off, 16);
            if (lane >= off) y += t;
        }
        wsum[lane] = y - s;
    }
    __syncthreads();
    int excl = x - v + wsum[wid] + bpre[blockIdx.x];
    rowptr[base + tid] = excl;
    cursor[base + tid] = excl;
}

// ---------------------------------------------------------------------------
// CSR build: scatter edges, packed (col, val) int2 single 8B write
__global__ void scatter_edges(const int* __restrict__ rows, const int* __restrict__ cols,
                              const float* __restrict__ vals, int* __restrict__ cursor,
                              int2* __restrict__ cev) {
    int e = blockIdx.x * 256 + threadIdx.x;
    if (e >= NNZ) return;
    int r = rows[e];
    int p = atomicAdd(&cursor[r], 1);
    int2 pk;
    pk.x = cols[e];
    pk.y = __float_as_int(vals[e]);
    cev[p] = pk;
}

// ---------------------------------------------------------------------------
// bf16 gather SpMM: wave per row, lane owns dword `lane` of the row.
// y[r] = sum val * x[col]          (COMBINE=0)
// y[r] = 2*sum - xm2[r]            (COMBINE=1)
template <int COMBINE>
__global__ void spmm_gather(const int* __restrict__ rowptr, const int2* __restrict__ cev,
                            const unsigned int* __restrict__ x,
                            const unsigned int* __restrict__ xm2,
                            unsigned int* __restrict__ y) {
    int row = (blockIdx.x * 256 + threadIdx.x) >> 6;
    int lane = threadIdx.x & 63;
    if (row >= V) return;
    int s = rowptr[row];
    int e = rowptr[row + 1];
    float ax = 0.0f, ay = 0.0f;
    int i = s;
    int e4 = s + ((e - s) & ~3);
    for (; i < e4; i += 4) {
        int2 e0 = cev[i], e1 = cev[i + 1], e2 = cev[i + 2], e3 = cev[i + 3];
        unsigned int u0 = x[(size_t)e0.x * ROWU + lane];
        unsigned int u1 = x[(size_t)e1.x * ROWU + lane];
        unsigned int u2 = x[(size_t)e2.x * ROWU + lane];
        unsigned int u3 = x[(size_t)e3.x * ROWU + lane];
        float v0 = __int_as_float(e0.y), v1 = __int_as_float(e1.y);
        float v2 = __int_as_float(e2.y), v3 = __int_as_float(e3.y);
        ax = fmaf(v0, bflo(u0), ax);
        ay = fmaf(v0, bfhi(u0), ay);
        ax = fmaf(v1, bflo(u1), ax);
        ay = fmaf(v1, bfhi(u1), ay);
        ax = fmaf(v2, bflo(u2), ax);
        ay = fmaf(v2, bfhi(u2), ay);
        ax = fmaf(v3, bflo(u3), ax);
        ay = fmaf(v3, bfhi(u3), ay);
    }
    for (; i < e; ++i) {
        int2 ee = cev[i];
        unsigned int u = x[(size_t)ee.x * ROWU + lane];
        float v = __int_as_float(ee.y);
        ax = fmaf(v, bflo(u), ax);
        ay = fmaf(v, bfhi(u), ay);
    }
    if (COMBINE) {
        unsigned int m = xm2[(size_t)row * ROWU + lane];
        ax = 2.0f * ax - bflo(m);
        ay = 2.0f * ay - bfhi(m);
    }
    y[(size_t)row * ROWU + lane] = f2bf(ax) | (f2bf(ay) << 16);
}

// ---------------------------------------------------------------------------
// MFMA fused output contraction. Wave = 16 vertices x 64 outs x 4 batches.
// Per b: out_b[v,o] = bias[o] + sum_k sum_fin x_k[v][b*32+fin] * W[(fin*5+k)*64+o]
// A-frag: lane l holds x[v0+(l&15)][b*32 + (l>>4)*8 .. +8]  (one 16B load)
// B-frag: prebuilt wfh/wfl (split precision)
// C/D:    col=lane&15, row=(lane>>4)*4+reg   [m89-verified mapping]
__global__ __launch_bounds__(256) void fused_mfma(
    const unsigned short* __restrict__ x0, const unsigned short* __restrict__ x1,
    const unsigned short* __restrict__ x2, const unsigned short* __restrict__ x3,
    const unsigned short* __restrict__ x4, const uint4* __restrict__ wfh,
    const uint4* __restrict__ wfl, const float* __restrict__ bias,
    float* __restrict__ out) {
    const int tid = threadIdx.x;
    const int lane = tid & 63;
    const int g = (blockIdx.x * 256 + tid) >> 6;  // wave id < V/16 = 12288
    const int v0 = g << 4;
    const int col = lane & 15;
    const int quad = lane >> 4;
    const unsigned short* const xs[K] = {x0, x1, x2, x3, x4};

    f32x4 acc[B][4];
#pragma unroll
    for (int b = 0; b < B; ++b)
#pragma unroll
        for (int nt = 0; nt < 4; ++nt) acc[b][nt] = (f32x4){0.f, 0.f, 0.f, 0.f};

#pragma unroll
    for (int k = 0; k < K; ++k) {
        const unsigned short* xk = xs[k] + ((size_t)(v0 + col)) * C + quad * 8;
        bf16x8 a0 = *reinterpret_cast<const bf16x8*>(xk);
        bf16x8 a1 = *reinterpret_cast<const bf16x8*>(xk + 32);
        bf16x8 a2 = *reinterpret_cast<const bf16x8*>(xk + 64);
        bf16x8 a3 = *reinterpret_cast<const bf16x8*>(xk + 96);
#pragma unroll
        for (int nt = 0; nt < 4; ++nt) {
            uint4 uh = wfh[(k * 4 + nt) * 64 + lane];
            uint4 ul = wfl[(k * 4 + nt) * 64 + lane];
            bf16x8 wh = *reinterpret_cast<bf16x8*>(&uh);
            bf16x8 wl = *reinterpret_cast<bf16x8*>(&ul);
            acc[0][nt] = __builtin_amdgcn_mfma_f32_16x16x32_bf16(a0, wh, acc[0][nt], 0, 0, 0);
            acc[1][nt] = __builtin_amdgcn_mfma_f32_16x16x32_bf16(a1, wh, acc[1][nt], 0, 0, 0);
            acc[2][nt] = __builtin_amdgcn_mfma_f32_16x16x32_bf16(a2, wh, acc[2][nt], 0, 0, 0);
            acc[3][nt] = __builtin_amdgcn_mfma_f32_16x16x32_bf16(a3, wh, acc[3][nt], 0, 0, 0);
            acc[0][nt] = __builtin_amdgcn_mfma_f32_16x16x32_bf16(a0, wl, acc[0][nt], 0, 0, 0);
            acc[1][nt] = __builtin_amdgcn_mfma_f32_16x16x32_bf16(a1, wl, acc[1][nt], 0, 0, 0);
            acc[2][nt] = __builtin_amdgcn_mfma_f32_16x16x32_bf16(a2, wl, acc[2][nt], 0, 0, 0);
            acc[3][nt] = __builtin_amdgcn_mfma_f32_16x16x32_bf16(a3, wl, acc[3][nt], 0, 0, 0);
        }
    }

    float bv[4];
#pragma unroll
    for (int nt = 0; nt < 4; ++nt) bv[nt] = bias[nt * 16 + col];
#pragma unroll
    for (int b = 0; b < B; ++b)
#pragma unroll
        for (int nt = 0; nt < 4; ++nt)
#pragma unroll
            for (int r = 0; r < 4; ++r) {
                int row = quad * 4 + r;
                out[((size_t)b * V + v0 + row) * FOUT + nt * 16 + col] = acc[b][nt][r] + bv[nt];
            }
}

// ---------------------------------------------------------------------------
extern "C" void kernel_launch(void* const* d_in, const int* in_sizes, int n_in,
                              void* d_out, int out_size, void* d_ws, size_t ws_size,
                              hipStream_t stream) {
    const int* lap_rows = (const int*)d_in[0];
    const int* lap_cols = (const int*)d_in[1];
    const float* lap_vals = (const float*)d_in[2];
    const float* inputs = (const float*)d_in[3];
    const float* weight = (const float*)d_in[4];  // flat [160][64] == effective W
    const float* bias = (const float*)d_in[5];
    float* out = (float*)d_out;

    char* p = (char*)d_ws;
    auto alloc = [&](size_t bytes) {
        char* r = p;
        p += (bytes + 511) & ~(size_t)511;
        return r;
    };
    int* rowptr = (int*)alloc((size_t)(V + 1) * 4);
    int* cursor = (int*)alloc((size_t)V * 4);
    int* bsum = (int*)alloc(192 * 4);
    int* bpre = (int*)alloc(192 * 4);
    uint4* wfh = (uint4*)alloc((size_t)K * 4 * 64 * 16);
    uint4* wfl = (uint4*)alloc((size_t)K * 4 * 64 * 16);
    int2* cev = (int2*)alloc((size_t)NNZ * 8);
    unsigned int* xb0 = (unsigned int*)alloc((size_t)V * ROWU * 4);
    unsigned int* xb1 = (unsigned int*)alloc((size_t)V * ROWU * 4);
    unsigned int* xb2 = (unsigned int*)alloc((size_t)V * ROWU * 4);
    unsigned int* xb3 = (unsigned int*)alloc((size_t)V * ROWU * 4);
    unsigned int* xb4 = (unsigned int*)alloc((size_t)V * ROWU * 4);

    const int edge_blocks = (NNZ + 255) / 256;
    const int x0_blocks = (V * 64) / 256;
    const int spmm_blocks = (V * 64) / 256;
    const int mfma_blocks = (V / 16) * 64 / 256;  // 3072

    // ---- CSR build ----
    hipMemsetAsync(cursor, 0, (size_t)V * 4, stream);
    hist_rows<<<edge_blocks, 256, 0, stream>>>(lap_rows, cursor);
    chunk_sums<<<V / 1024, 1024, 0, stream>>>(cursor, bsum);
    scan_sums<<<1, 256, 0, stream>>>(bsum, bpre, rowptr);
    scan_chunks<<<V / 1024, 1024, 0, stream>>>(cursor, bpre, rowptr, cursor);
    scatter_edges<<<edge_blocks, 256, 0, stream>>>(lap_rows, lap_cols, lap_vals, cursor, cev);

    // ---- x0 (bf16, b-major rows) + W fragments ----
    build_x0<<<x0_blocks, 256, 0, stream>>>(inputs, xb0);
    build_wfrag<<<5, 256, 0, stream>>>(weight, wfh, wfl);

    // ---- Chebyshev recurrence (bf16 storage, f32 accumulate) ----
    spmm_gather<0><<<spmm_blocks, 256, 0, stream>>>(rowptr, cev, xb0, nullptr, xb1);
    spmm_gather<1><<<spmm_blocks, 256, 0, stream>>>(rowptr, cev, xb1, xb0, xb2);
    spmm_gather<1><<<spmm_blocks, 256, 0, stream>>>(rowptr, cev, xb2, xb1, xb3);
    spmm_gather<1><<<spmm_blocks, 256, 0, stream>>>(rowptr, cev, xb3, xb2, xb4);

    // ---- fused MFMA output contraction ----
    fused_mfma<<<mfma_blocks, 256, 0, stream>>>(
        (const unsigned short*)xb0, (const unsigned short*)xb1, (const unsigned short*)xb2,
        (const unsigned short*)xb3, (const unsigned short*)xb4, wfh, wfl, bias, out);
}

// Round 7
// 651.236 us; speedup vs baseline: 12.4084x; 1.1484x over previous
//
#include <hip/hip_runtime.h>

#define V 196608
#define NNZ (9 * V)
#define B 4
#define FIN 32
#define FOUT 64
#define K 5
#define C 128            // FIN*B feature columns per vertex
#define ROWU 64          // uints per bf16 row (128 feats * 2B / 4B)
#define SPMM_BLOCKS 2048 // persistent grid: 8 blocks/CU * 256 CU

typedef __attribute__((ext_vector_type(8))) short bf16x8;
typedef __attribute__((ext_vector_type(4))) float f32x4;

// ---- bf16 helpers (bit-level, RNE) ---------------------------------------
static __device__ __forceinline__ unsigned int f2bf(float f) {
    union { float f; unsigned int u; } v; v.f = f;
    return (v.u + 0x7FFFu + ((v.u >> 16) & 1u)) >> 16;
}
static __device__ __forceinline__ float bflo(unsigned int u) {
    union { unsigned int u; float f; } v; v.u = u << 16; return v.f;
}
static __device__ __forceinline__ float bfhi(unsigned int u) {
    union { unsigned int u; float f; } v; v.u = u & 0xFFFF0000u; return v.f;
}

// ---------------------------------------------------------------------------
// x0[v][b*32+fin] (bf16, b-major row) = inputs[(b*V+v)*32+fin]
__global__ void build_x0(const float* __restrict__ inp, unsigned int* __restrict__ x0) {
    int t = blockIdx.x * 256 + threadIdx.x;
    if (t >= V * 64) return;
    int d = t & 63;
    int v = t >> 6;
    int b = d >> 4;
    int fin = (d & 15) * 2;
    const float* s = inp + ((size_t)b * V + v) * 32 + fin;
    float f0 = s[0], f1 = s[1];
    x0[(size_t)v * ROWU + d] = f2bf(f0) | (f2bf(f1) << 16);
}

// ---------------------------------------------------------------------------
// W fragment prep: split-precision bf16 B-fragments, k-major K ordering.
__global__ void build_wfrag(const float* __restrict__ w, uint4* __restrict__ wfh,
                            uint4* __restrict__ wfl) {
    int idx = blockIdx.x * 256 + threadIdx.x;
    if (idx >= K * 4 * 64) return;
    int lane = idx & 63;
    int nt = (idx >> 6) & 3;
    int k = idx >> 8;
    int col = lane & 15;
    int quad = lane >> 4;
    int o = nt * 16 + col;
    unsigned int hh[8], ll[8];
#pragma unroll
    for (int e = 0; e < 8; ++e) {
        int fin = quad * 8 + e;
        float wv = w[(fin * 5 + k) * 64 + o];
        unsigned int hb = f2bf(wv);
        float hf = bflo(hb);
        ll[e] = f2bf(wv - hf);
        hh[e] = hb;
    }
    uint4 uh, ul;
    uh.x = hh[0] | (hh[1] << 16);
    uh.y = hh[2] | (hh[3] << 16);
    uh.z = hh[4] | (hh[5] << 16);
    uh.w = hh[6] | (hh[7] << 16);
    ul.x = ll[0] | (ll[1] << 16);
    ul.y = ll[2] | (ll[3] << 16);
    ul.z = ll[4] | (ll[5] << 16);
    ul.w = ll[6] | (ll[7] << 16);
    wfh[idx] = uh;
    wfl[idx] = ul;
}

// ---------------------------------------------------------------------------
// CSR build step 1: histogram row counts into cnt[] (pre-zeroed)
__global__ void hist_rows(const int* __restrict__ rows, int* __restrict__ cnt) {
    int e = blockIdx.x * 256 + threadIdx.x;
    if (e < NNZ) atomicAdd(&cnt[rows[e]], 1);
}

// ---------------------------------------------------------------------------
// parallel scan phase A: per-1024-chunk sums
__global__ void chunk_sums(const int* __restrict__ cnt, int* __restrict__ bsum) {
    __shared__ int ws[16];
    int tid = threadIdx.x;
    int lane = tid & 63;
    int wid = tid >> 6;
    int v = cnt[blockIdx.x * 1024 + tid];
#pragma unroll
    for (int off = 32; off >= 1; off >>= 1) v += __shfl_down(v, off, 64);
    if (lane == 0) ws[wid] = v;
    __syncthreads();
    if (tid < 16) {
        int s = ws[tid];
#pragma unroll
        for (int off = 8; off >= 1; off >>= 1) s += __shfl_down(s, off, 16);
        if (tid == 0) bsum[blockIdx.x] = s;
    }
}

// ---------------------------------------------------------------------------
// parallel scan phase B: exclusive scan of 192 chunk sums
__global__ void scan_sums(const int* __restrict__ bsum, int* __restrict__ bpre,
                          int* __restrict__ rowptr) {
    __shared__ int ws[4];
    int tid = threadIdx.x;
    int lane = tid & 63;
    int wid = tid >> 6;
    int v = (tid < 192) ? bsum[tid] : 0;
    int x = v;
#pragma unroll
    for (int off = 1; off < 64; off <<= 1) {
        int t = __shfl_up(x, off, 64);
        if (lane >= off) x += t;
    }
    if (lane == 63) ws[wid] = x;
    __syncthreads();
    if (wid == 0 && lane < 4) {
        int s = ws[lane];
        int y = s;
#pragma unroll
        for (int off = 1; off < 4; off <<= 1) {
            int t = __shfl_up(y, off, 4);
            if (lane >= off) y += t;
        }
        ws[lane] = y - s;
    }
    __syncthreads();
    int incl = x + ws[wid];
    if (tid < 192) bpre[tid] = incl - v;
    if (tid == 191) rowptr[V] = incl;
}

// ---------------------------------------------------------------------------
// parallel scan phase C: per-chunk scan + chunk prefix
__global__ void scan_chunks(const int* __restrict__ cnt, const int* __restrict__ bpre,
                            int* __restrict__ rowptr, int* __restrict__ cursor) {
    __shared__ int wsum[16];
    int tid = threadIdx.x;
    int lane = tid & 63;
    int wid = tid >> 6;
    int base = blockIdx.x * 1024;
    int v = cnt[base + tid];
    int x = v;
#pragma unroll
    for (int off = 1; off < 64; off <<= 1) {
        int t = __shfl_up(x, off, 64);
        if (lane >= off) x += t;
    }
    if (lane == 63) wsum[wid] = x;
    __syncthreads();
    if (wid == 0 && lane < 16) {
        int s = wsum[lane];
        int y = s;
#pragma unroll
        for (int off = 1; off < 16; off <<= 1) {
            int t = __shfl_up(y, off, 16);
            if (lane >= off) y += t;
        }
        wsum[lane] = y - s;
    }
    __syncthreads();
    int excl = x - v + wsum[wid] + bpre[blockIdx.x];
    rowptr[base + tid] = excl;
    cursor[base + tid] = excl;
}

// ---------------------------------------------------------------------------
// windowed CSR scatter: pass only handles rows in [lo, hi) so cev writes and
// cursor atomics concentrate in an L2-hot window (kills 64B-line write amp).
__global__ void scatter_edges_win(const int* __restrict__ rows, const int* __restrict__ cols,
                                  const float* __restrict__ vals, int* __restrict__ cursor,
                                  int2* __restrict__ cev, int lo, int hi) {
    int e = blockIdx.x * 256 + threadIdx.x;
    if (e >= NNZ) return;
    int r = rows[e];
    if (r < lo || r >= hi) return;
    int p = atomicAdd(&cursor[r], 1);
    int2 pk;
    pk.x = cols[e];
    pk.y = __float_as_int(vals[e]);
    cev[p] = pk;
}

// ---------------------------------------------------------------------------
// bf16 gather SpMM v3: persistent waves, 2 rows per iteration, joint 4+4
// strip-mine -> up to 8 gathers in flight per wave.
// y[r] = sum val * x[col]          (COMBINE=0)
// y[r] = 2*sum - xm2[r]            (COMBINE=1)
template <int COMBINE>
__global__ __launch_bounds__(256) void spmm_gather(
    const int* __restrict__ rowptr, const int2* __restrict__ cev,
    const unsigned int* __restrict__ x, const unsigned int* __restrict__ xm2,
    unsigned int* __restrict__ y) {
    const int lane = threadIdx.x & 63;
    const int wid0 = (blockIdx.x * 256 + threadIdx.x) >> 6;
    const int NW = SPMM_BLOCKS * 4;  // total waves
    for (int base = wid0 * 2; base < V; base += NW * 2) {
        const int r0 = base, r1 = base + 1;
        const int s0 = rowptr[r0];
        const int e0 = rowptr[r0 + 1];
        const int e1 = rowptr[r1 + 1];  // s1 == e0
        float ax0 = 0.f, ay0 = 0.f, ax1 = 0.f, ay1 = 0.f;
        int i0 = s0, i1 = e0;
        // joint main loop: 4 edges from each row -> 8 outstanding gathers
        while (e0 - i0 >= 4 && e1 - i1 >= 4) {
            int2 Ea[4], Eb[4];
#pragma unroll
            for (int j = 0; j < 4; ++j) {
                Ea[j] = cev[i0 + j];
                Eb[j] = cev[i1 + j];
            }
            unsigned int Ua[4], Ub[4];
#pragma unroll
            for (int j = 0; j < 4; ++j) {
                Ua[j] = x[(size_t)Ea[j].x * ROWU + lane];
                Ub[j] = x[(size_t)Eb[j].x * ROWU + lane];
            }
#pragma unroll
            for (int j = 0; j < 4; ++j) {
                float va = __int_as_float(Ea[j].y);
                float vb = __int_as_float(Eb[j].y);
                ax0 = fmaf(va, bflo(Ua[j]), ax0);
                ay0 = fmaf(va, bfhi(Ua[j]), ay0);
                ax1 = fmaf(vb, bflo(Ub[j]), ax1);
                ay1 = fmaf(vb, bfhi(Ub[j]), ay1);
            }
            i0 += 4;
            i1 += 4;
        }
        // drains (<=3 edges each typical)
        for (; i0 + 2 <= e0; i0 += 2) {
            int2 a = cev[i0], b = cev[i0 + 1];
            unsigned int u0 = x[(size_t)a.x * ROWU + lane];
            unsigned int u1 = x[(size_t)b.x * ROWU + lane];
            float v0 = __int_as_float(a.y), v1 = __int_as_float(b.y);
            ax0 = fmaf(v0, bflo(u0), ax0);
            ay0 = fmaf(v0, bfhi(u0), ay0);
            ax0 = fmaf(v1, bflo(u1), ax0);
            ay0 = fmaf(v1, bfhi(u1), ay0);
        }
        for (; i0 < e0; ++i0) {
            int2 a = cev[i0];
            unsigned int u = x[(size_t)a.x * ROWU + lane];
            float v = __int_as_float(a.y);
            ax0 = fmaf(v, bflo(u), ax0);
            ay0 = fmaf(v, bfhi(u), ay0);
        }
        for (; i1 + 2 <= e1; i1 += 2) {
            int2 a = cev[i1], b = cev[i1 + 1];
            unsigned int u0 = x[(size_t)a.x * ROWU + lane];
            unsigned int u1 = x[(size_t)b.x * ROWU + lane];
            float v0 = __int_as_float(a.y), v1 = __int_as_float(b.y);
            ax1 = fmaf(v0, bflo(u0), ax1);
            ay1 = fmaf(v0, bfhi(u0), ay1);
            ax1 = fmaf(v1, bflo(u1), ax1);
            ay1 = fmaf(v1, bfhi(u1), ay1);
        }
        for (; i1 < e1; ++i1) {
            int2 a = cev[i1];
            unsigned int u = x[(size_t)a.x * ROWU + lane];
            float v = __int_as_float(a.y);
            ax1 = fmaf(v, bflo(u), ax1);
            ay1 = fmaf(v, bfhi(u), ay1);
        }
        if (COMBINE) {
            unsigned int m0 = xm2[(size_t)r0 * ROWU + lane];
            unsigned int m1 = xm2[(size_t)r1 * ROWU + lane];
            ax0 = 2.0f * ax0 - bflo(m0);
            ay0 = 2.0f * ay0 - bfhi(m0);
            ax1 = 2.0f * ax1 - bflo(m1);
            ay1 = 2.0f * ay1 - bfhi(m1);
        }
        y[(size_t)r0 * ROWU + lane] = f2bf(ax0) | (f2bf(ay0) << 16);
        y[(size_t)r1 * ROWU + lane] = f2bf(ax1) | (f2bf(ay1) << 16);
    }
}

// ---------------------------------------------------------------------------
// MFMA fused output contraction. Wave = 16 vertices x 64 outs x 4 batches.
// A-frag: lane l holds x[v0+(l&15)][b*32 + (l>>4)*8 .. +8]  (one 16B load)
// C/D:    col=lane&15, row=(lane>>4)*4+reg   [m89-verified mapping]
__global__ __launch_bounds__(256) void fused_mfma(
    const unsigned short* __restrict__ x0, const unsigned short* __restrict__ x1,
    const unsigned short* __restrict__ x2, const unsigned short* __restrict__ x3,
    const unsigned short* __restrict__ x4, const uint4* __restrict__ wfh,
    const uint4* __restrict__ wfl, const float* __restrict__ bias,
    float* __restrict__ out) {
    const int tid = threadIdx.x;
    const int lane = tid & 63;
    const int g = (blockIdx.x * 256 + tid) >> 6;
    const int v0 = g << 4;
    const int col = lane & 15;
    const int quad = lane >> 4;
    const unsigned short* const xs[K] = {x0, x1, x2, x3, x4};

    f32x4 acc[B][4];
#pragma unroll
    for (int b = 0; b < B; ++b)
#pragma unroll
        for (int nt = 0; nt < 4; ++nt) acc[b][nt] = (f32x4){0.f, 0.f, 0.f, 0.f};

#pragma unroll
    for (int k = 0; k < K; ++k) {
        const unsigned short* xk = xs[k] + ((size_t)(v0 + col)) * C + quad * 8;
        bf16x8 a0 = *reinterpret_cast<const bf16x8*>(xk);
        bf16x8 a1 = *reinterpret_cast<const bf16x8*>(xk + 32);
        bf16x8 a2 = *reinterpret_cast<const bf16x8*>(xk + 64);
        bf16x8 a3 = *reinterpret_cast<const bf16x8*>(xk + 96);
#pragma unroll
        for (int nt = 0; nt < 4; ++nt) {
            uint4 uh = wfh[(k * 4 + nt) * 64 + lane];
            uint4 ul = wfl[(k * 4 + nt) * 64 + lane];
            bf16x8 wh = *reinterpret_cast<bf16x8*>(&uh);
            bf16x8 wl = *reinterpret_cast<bf16x8*>(&ul);
            acc[0][nt] = __builtin_amdgcn_mfma_f32_16x16x32_bf16(a0, wh, acc[0][nt], 0, 0, 0);
            acc[1][nt] = __builtin_amdgcn_mfma_f32_16x16x32_bf16(a1, wh, acc[1][nt], 0, 0, 0);
            acc[2][nt] = __builtin_amdgcn_mfma_f32_16x16x32_bf16(a2, wh, acc[2][nt], 0, 0, 0);
            acc[3][nt] = __builtin_amdgcn_mfma_f32_16x16x32_bf16(a3, wh, acc[3][nt], 0, 0, 0);
            acc[0][nt] = __builtin_amdgcn_mfma_f32_16x16x32_bf16(a0, wl, acc[0][nt], 0, 0, 0);
            acc[1][nt] = __builtin_amdgcn_mfma_f32_16x16x32_bf16(a1, wl, acc[1][nt], 0, 0, 0);
            acc[2][nt] = __builtin_amdgcn_mfma_f32_16x16x32_bf16(a2, wl, acc[2][nt], 0, 0, 0);
            acc[3][nt] = __builtin_amdgcn_mfma_f32_16x16x32_bf16(a3, wl, acc[3][nt], 0, 0, 0);
        }
    }

    float bv[4];
#pragma unroll
    for (int nt = 0; nt < 4; ++nt) bv[nt] = bias[nt * 16 + col];
#pragma unroll
    for (int b = 0; b < B; ++b)
#pragma unroll
        for (int nt = 0; nt < 4; ++nt)
#pragma unroll
            for (int r = 0; r < 4; ++r) {
                int row = quad * 4 + r;
                out[((size_t)b * V + v0 + row) * FOUT + nt * 16 + col] = acc[b][nt][r] + bv[nt];
            }
}

// ---------------------------------------------------------------------------
extern "C" void kernel_launch(void* const* d_in, const int* in_sizes, int n_in,
                              void* d_out, int out_size, void* d_ws, size_t ws_size,
                              hipStream_t stream) {
    const int* lap_rows = (const int*)d_in[0];
    const int* lap_cols = (const int*)d_in[1];
    const float* lap_vals = (const float*)d_in[2];
    const float* inputs = (const float*)d_in[3];
    const float* weight = (const float*)d_in[4];  // flat [160][64] == effective W
    const float* bias = (const float*)d_in[5];
    float* out = (float*)d_out;

    char* p = (char*)d_ws;
    auto alloc = [&](size_t bytes) {
        char* r = p;
        p += (bytes + 511) & ~(size_t)511;
        return r;
    };
    int* rowptr = (int*)alloc((size_t)(V + 1) * 4);
    int* cursor = (int*)alloc((size_t)V * 4);
    int* bsum = (int*)alloc(192 * 4);
    int* bpre = (int*)alloc(192 * 4);
    uint4* wfh = (uint4*)alloc((size_t)K * 4 * 64 * 16);
    uint4* wfl = (uint4*)alloc((size_t)K * 4 * 64 * 16);
    int2* cev = (int2*)alloc((size_t)NNZ * 8);
    unsigned int* xb0 = (unsigned int*)alloc((size_t)V * ROWU * 4);
    unsigned int* xb1 = (unsigned int*)alloc((size_t)V * ROWU * 4);
    unsigned int* xb2 = (unsigned int*)alloc((size_t)V * ROWU * 4);
    unsigned int* xb3 = (unsigned int*)alloc((size_t)V * ROWU * 4);
    unsigned int* xb4 = (unsigned int*)alloc((size_t)V * ROWU * 4);

    const int edge_blocks = (NNZ + 255) / 256;
    const int x0_blocks = (V * 64) / 256;
    const int mfma_blocks = (V / 16) * 64 / 256;  // 3072

    // ---- CSR build ----
    hipMemsetAsync(cursor, 0, (size_t)V * 4, stream);
    hist_rows<<<edge_blocks, 256, 0, stream>>>(lap_rows, cursor);
    chunk_sums<<<V / 1024, 1024, 0, stream>>>(cursor, bsum);
    scan_sums<<<1, 256, 0, stream>>>(bsum, bpre, rowptr);
    scan_chunks<<<V / 1024, 1024, 0, stream>>>(cursor, bpre, rowptr, cursor);
    // windowed scatter: 4 passes over row ranges (write locality)
    for (int w = 0; w < 4; ++w) {
        scatter_edges_win<<<edge_blocks, 256, 0, stream>>>(
            lap_rows, lap_cols, lap_vals, cursor, cev, w * (V / 4), (w + 1) * (V / 4));
    }

    // ---- x0 (bf16, b-major rows) + W fragments ----
    build_x0<<<x0_blocks, 256, 0, stream>>>(inputs, xb0);
    build_wfrag<<<5, 256, 0, stream>>>(weight, wfh, wfl);

    // ---- Chebyshev recurrence (bf16 storage, f32 accumulate) ----
    spmm_gather<0><<<SPMM_BLOCKS, 256, 0, stream>>>(rowptr, cev, xb0, nullptr, xb1);
    spmm_gather<1><<<SPMM_BLOCKS, 256, 0, stream>>>(rowptr, cev, xb1, xb0, xb2);
    spmm_gather<1><<<SPMM_BLOCKS, 256, 0, stream>>>(rowptr, cev, xb2, xb1, xb3);
    spmm_gather<1><<<SPMM_BLOCKS, 256, 0, stream>>>(rowptr, cev, xb3, xb2, xb4);

    // ---- fused MFMA output contraction ----
    fused_mfma<<<mfma_blocks, 256, 0, stream>>>(
        (const unsigned short*)xb0, (const unsigned short*)xb1, (const unsigned short*)xb2,
        (const unsigned short*)xb3, (const unsigned short*)xb4, wfh, wfl, bias, out);
}